// Round 11
// baseline (93.133 us; speedup 1.0000x reference)
//
#include <hip/hip_runtime.h>
#include <hip/hip_bf16.h>

// out[n,v] = x[n,v] + sum_{c<v} x[n,c] * sum_k B_k(x[n,c]) * params[k, v(v-1)/2+c]
// GEMM form: G[n][c*16+k] = x[n,c]*B_k(x[n,c]);  W2T[v][c*16+k] = params or 0
// R11: shuffle-free. Lane (s,q) computes channel c = 2t+(q>>1) per K-tile t
// (pair q,q^1 redundantly computes the same channel; each keeps its own
// 8-slot half-window via the XOR-folded barrel -> B0..B3). Inner loop is pure
// VALU->MFMA: no DS ops, no cross-lane. B-frags 24 x f16x8, (256,2) bound
// guarantees register residency (no remat). 512 blocks x 4 tiles/wave.

#define PPAIR 496

typedef _Float16 f16x8 __attribute__((ext_vector_type(8)));
typedef float f32x4 __attribute__((ext_vector_type(4)));
typedef unsigned int u32;
typedef unsigned int u32x4 __attribute__((ext_vector_type(4)));

// ---- prep: build W2T [32][512] f16 from params [16][496] f32 (c-fastest: coalesced)
__global__ __launch_bounds__(256) void prep_w2t(const float* __restrict__ params,
                                                unsigned short* __restrict__ w2t) {
    int i = blockIdx.x * 256 + threadIdx.x;   // 0 .. 16383
    int c = i & 31;
    int k = (i >> 5) & 15;
    int v = i >> 9;
    float w = 0.0f;
    if (c < v) w = params[k * PPAIR + (v * (v - 1)) / 2 + c];
    _Float16 h = (_Float16)w;
    w2t[v * 512 + c * 16 + k] = __builtin_bit_cast(unsigned short, h);
}

__global__ __launch_bounds__(256, 2) void decor_main(const float* __restrict__ xin,
                                                     const unsigned short* __restrict__ w2t,
                                                     float* __restrict__ out) {
    const int tid = threadIdx.x;
    const int wv = tid >> 6;
    const int l = tid & 63;
    const int s = l & 15;           // MFMA row/col lane id
    const int q = l >> 4;           // quarter-wave id (K-slot group)
    const int qp = q & 1;           // window parity: keeps k-slots [8qp, 8qp+8) of its channel
    const int qh = q >> 1;          // channel parity: c = 2t + qh

    // ---- B fragments in registers: bfrag[t] = W2T[v'][32t + 8q .. +8) (16B contiguous)
    f16x8 b1[16];   // v' = 16+s (out cols 16..31), all t
    f16x8 b0[8];    // v' = s    (out cols 0..15), t<8 only (c<=15 since c<v<=15)
#pragma unroll
    for (int t = 0; t < 16; ++t) {
        b1[t] = *(const f16x8*)(w2t + (16 + s) * 512 + t * 32 + q * 8);
        if (t < 8) b0[t] = *(const f16x8*)(w2t + s * 512 + t * 32 + q * 8);
    }

    const float sc = 13.0f / 12.0f;        // 1/h in u-space
    const int S0w = blockIdx.x * 256 + wv * 64;

    // ---- prime: tile 0 basis x-loads (lane reads its 16 channels of row s)
    float xv[16];
    {
        const float* xr = xin + (S0w + s) * 32 + qh;
#pragma unroll
        for (int t = 0; t < 16; ++t) xv[t] = xr[2 * t];
    }

#pragma unroll
    for (int tile = 0; tile < 4; ++tile) {
        const int T0 = S0w + tile * 16;

        // epilogue x for CURRENT tile — issue early
        float xe0[4], xe1[4];
#pragma unroll
        for (int rI = 0; rI < 4; ++rI) {
            int base = (T0 + q * 4 + rI) * 32;
            xe0[rI] = xin[base + s];
            xe1[rI] = xin[base + 16 + s];
        }
        // basis x for NEXT tile — issue before compute so latency hides
        float xvn[16];
        if (tile < 3) {
            const float* xr = xin + (T0 + 16 + s) * 32 + qh;
#pragma unroll
            for (int t = 0; t < 16; ++t) xvn[t] = xr[2 * t];
        }

        f32x4 acc0 = {0.f, 0.f, 0.f, 0.f};
        f32x4 acc1 = {0.f, 0.f, 0.f, 0.f};

#pragma unroll
        for (int t = 0; t < 16; ++t) {
            float x = xv[t];
            float uu = fmaf(x, sc, 6.5f);            // (x+6)*13/12, clamp in u-space
            uu = fminf(fmaxf(uu, 0.0f), 12.999987f); // == clip(x,-6,5.999988) (v_med3)
            int mi = (int)uu;                        // span 0..12; nonzero basis mi..mi+3
            float mf = (float)mi;
            float r = uu - mf;                       // in [0,1)
            float N0, N1, N2, N3;
            if (__all(mi >= 3 && mi <= 9)) {
                // interior span: uniform cubic B-spline closed form
                float omr = 1.0f - r;
                float r2 = r * r, r3 = r2 * r;
                float o2 = omr * omr;
                N0 = o2 * omr * (1.0f / 6.0f);
                N3 = r3 * (1.0f / 6.0f);
                N1 = fmaf(0.5f, r3, (2.0f / 3.0f) - r2);
                N2 = 1.0f - N0 - N1 - N3;
            } else {
                // general clamped-knot recursion in u-space (integer knot gaps)
                float t13 = 13.0f - mf;
                float af = fminf(mf, 1.0f);
                float bf = fminf(mf, 2.0f);
                float cf = fminf(t13, 2.0f);
                float df = fminf(t13, 3.0f);
                float r1 = 1.0f - r;
                float l2 = r + af, rr2 = cf - r;
                float l3 = r + bf, rr3 = df - r;
                // deg 2
                float iv = (af == 0.0f) ? 1.0f : 0.5f;          // 1/(1+a)
                float T = r1 * iv;
                float M0 = r1 * T;
                float sv = l2 * T;
                float iv2 = (cf == 1.0f) ? 1.0f : 0.5f;         // 1/c2
                float T2 = r * iv2;
                float M1 = fmaf(rr2, T2, sv);
                float M2 = r * T2;
                // deg 3
                float iv3 = 0.5f;
                iv3 = (bf == 0.0f) ? 1.0f : iv3;                // 1/(1+b)
                iv3 = (bf == 2.0f) ? (1.0f / 3.0f) : iv3;
                T = M0 * iv3;
                N0 = r1 * T;
                sv = l3 * T;
                float g14 = af + cf;                            // a+c2 in {2,3}
                float iv4 = (g14 == 2.0f) ? 0.5f : (1.0f / 3.0f);
                T = M1 * iv4;
                N1 = fmaf(rr2, T, sv);
                sv = l2 * T;
                float iv5 = 0.5f;
                iv5 = (df == 1.0f) ? 1.0f : iv5;                // 1/d3
                iv5 = (df == 3.0f) ? (1.0f / 3.0f) : iv5;
                T = M2 * iv5;
                N2 = fmaf(rr3, T, sv);
                N3 = r * T;
            }
            // payload: g at f16 slots mi..mi+3 (dword pairs)
            float g0 = x * N0, g1 = x * N1, g2 = x * N2, g3 = x * N3;
            int e = mi & 1;
            float aa = e ? 0.0f : g0, bb = e ? g0 : g1;
            float cc = e ? g1 : g2, dd = e ? g2 : g3;
            float ee = e ? g3 : 0.0f;
            u32 p0 = __builtin_bit_cast(u32, __builtin_amdgcn_cvt_pkrtz(aa, bb));
            u32 p1 = __builtin_bit_cast(u32, __builtin_amdgcn_cvt_pkrtz(cc, dd));
            u32 p2 = __builtin_bit_cast(u32, __builtin_amdgcn_cvt_pkrtz(ee, 0.0f));
            int w0 = mi >> 1;
            int dlt = w0 & 1;
            // 4-dword container at even dword (w0&6), payload offset dlt
            u32 C0 = dlt ? 0u : p0;
            u32 C1 = dlt ? p0 : p1;
            u32 C2 = dlt ? p1 : p2;
            u32 C3 = dlt ? p2 : 0u;
            // XOR-folded barrel: B0..B3 = this lane's kept 4-dword window
            int j0 = (w0 & 6) ^ (qp << 2);
            bool b2 = (j0 & 2) != 0;
            u32 t0 = b2 ? 0u : C0;
            u32 t1 = b2 ? 0u : C1;
            u32 t2 = b2 ? C0 : C2;
            u32 t3 = b2 ? C1 : C3;
            u32 t4 = b2 ? C2 : 0u;
            u32 t5 = b2 ? C3 : 0u;
            bool b4 = (j0 & 4) != 0;
            u32 B0 = b4 ? t4 : t0;
            u32 B1 = b4 ? t5 : t1;
            u32 B2 = b4 ? 0u : t2;
            u32 B3 = b4 ? 0u : t3;
            u32x4 kp = {B0, B1, B2, B3};
            f16x8 ka = __builtin_bit_cast(f16x8, kp);
            acc1 = __builtin_amdgcn_mfma_f32_16x16x32_f16(ka, b1[t], acc1, 0, 0, 0);
            if (t < 8) {
                acc0 = __builtin_amdgcn_mfma_f32_16x16x32_f16(ka, b0[t], acc0, 0, 0, 0);
            }
        }

        // ---- epilogue: D[row=(q*4+r)][col=s(+16)] ; out = x + D
#pragma unroll
        for (int rI = 0; rI < 4; ++rI) {
            int sample = T0 + q * 4 + rI;
            int base = sample * 32;
            out[base + s]      = xe0[rI] + acc0[rI];
            out[base + 16 + s] = xe1[rI] + acc1[rI];
        }

        if (tile < 3) {
#pragma unroll
            for (int t = 0; t < 16; ++t) xv[t] = xvn[t];
        }
    }
}

extern "C" void kernel_launch(void* const* d_in, const int* in_sizes, int n_in,
                              void* d_out, int out_size, void* d_ws, size_t ws_size,
                              hipStream_t stream) {
    const float* xin = (const float*)d_in[0];
    const float* params = (const float*)d_in[1];
    float* out = (float*)d_out;
    unsigned short* w2t = (unsigned short*)d_ws;   // 32*512 f16 = 32 KB scratch

    prep_w2t<<<64, 256, 0, stream>>>(params, w2t);
    decor_main<<<512, 256, 0, stream>>>(xin, w2t, out);
}

// Round 13
// 90.138 us; speedup vs baseline: 1.0332x; 1.0332x over previous
//
#include <hip/hip_runtime.h>
#include <hip/hip_bf16.h>

// out[n,v] = x[n,v] + sum_{c<v} x[n,c] * sum_k B_k(x[n,c]) * params[k, v(v-1)/2+c]
// GEMM form: G[n][c*16+k] = x[n,c]*B_k(x[n,c]);  W2T[v][c*16+k] = params or 0
// R12 resubmit (broker timeout): K-split wave pairs. Wave h owns channels
// [16h,16h+16) of its 16-sample tile: 4 evals/lane (no redundancy), B-frags
// 16/8 (fits 128 VGPR -> 4 waves/SIMD). R5's verified eval/pack/shfl_xor(16)/
// MFMA logic verbatim. Cols 16-31 partials combined via small LDS + 1 barrier
// per tile. 2048 blocks x 2 tile-pairs.

#define PPAIR 496

typedef _Float16 f16x8 __attribute__((ext_vector_type(8)));
typedef float f32x4 __attribute__((ext_vector_type(4)));
typedef unsigned int u32;
typedef unsigned int u32x4 __attribute__((ext_vector_type(4)));

// ---- prep: build W2T [32][512] f16 from params [16][496] f32 (c-fastest: coalesced)
__global__ __launch_bounds__(256) void prep_w2t(const float* __restrict__ params,
                                                unsigned short* __restrict__ w2t) {
    int i = blockIdx.x * 256 + threadIdx.x;   // 0 .. 16383
    int c = i & 31;
    int k = (i >> 5) & 15;
    int v = i >> 9;
    float w = 0.0f;
    if (c < v) w = params[k * PPAIR + (v * (v - 1)) / 2 + c];
    _Float16 h = (_Float16)w;
    w2t[v * 512 + c * 16 + k] = __builtin_bit_cast(unsigned short, h);
}

__global__ __launch_bounds__(256, 4) void decor_main(const float* __restrict__ xin,
                                                     const unsigned short* __restrict__ w2t,
                                                     float* __restrict__ out) {
    // P[tile-parity][pair][(q*4+r)*17 + s] : cols16-31 partial from the h=0 wave
    __shared__ float P[2][2][16 * 17];

    const int tid = threadIdx.x;
    const int wv = tid >> 6;
    const int h = wv & 1;            // K-half this wave owns (channels 16h..16h+15)
    const int pair = wv >> 1;        // tile-pair id within block
    const int l = tid & 63;
    const int s = l & 15;            // MFMA row/col lane id
    const int q = l >> 4;            // quarter-wave id (K-slot group)
    const int qp = q & 1;            // pairing parity (partner = lane ^ 16)
    const int qh = q >> 1;
    const int sigma = 2 * qp + qh;   // channel offset within half: c = 16h + sigma + 4u

    // ---- B fragments, t-pairing swapped at load: t = 8h + 2u + (qp ? 1-e : e)
    f16x8 bA[4][2];   // v' = 16+s (out cols 16..31) — both halves
    f16x8 bB[4][2];   // v' = s    (out cols 0..15)  — h==0 only (c<16)
    const int tb = 8 * h;
#pragma unroll
    for (int u = 0; u < 4; ++u) {
#pragma unroll
        for (int e = 0; e < 2; ++e) {
            int t = tb + 2 * u + (qp ? (1 - e) : e);
            bA[u][e] = *(const f16x8*)(w2t + (16 + s) * 512 + t * 32 + q * 8);
            if (h == 0) bB[u][e] = *(const f16x8*)(w2t + s * 512 + t * 32 + q * 8);
        }
    }

    const float sc = 13.0f / 12.0f;        // 1/h in u-space
    const int Tbase = blockIdx.x * 64 + pair * 16;

    // ---- prime: tile 0 basis x-loads (4 channels of row s in this wave's half)
    float xv[4];
    {
        const float* xr = xin + (Tbase + s) * 32 + 16 * h + sigma;
#pragma unroll
        for (int u = 0; u < 4; ++u) xv[u] = xr[4 * u];
    }

#pragma unroll
    for (int i = 0; i < 2; ++i) {
        const int T0 = Tbase + i * 32;

        // epilogue x for CURRENT tile (this wave's output col = 16h + s)
        float xe[4];
#pragma unroll
        for (int rI = 0; rI < 4; ++rI)
            xe[rI] = xin[(T0 + q * 4 + rI) * 32 + 16 * h + s];

        // basis x for NEXT tile
        float xvn[4];
        if (i == 0) {
            const float* xr = xin + (Tbase + 32 + s) * 32 + 16 * h + sigma;
#pragma unroll
            for (int u = 0; u < 4; ++u) xvn[u] = xr[4 * u];
        }

        f32x4 acc0 = {0.f, 0.f, 0.f, 0.f};
        f32x4 acc1 = {0.f, 0.f, 0.f, 0.f};

#pragma unroll
        for (int u = 0; u < 4; ++u) {
            float x = xv[u];
            float uu = fmaf(x, sc, 6.5f);            // (x+6)*13/12, clamp in u-space
            uu = fminf(fmaxf(uu, 0.0f), 12.999987f); // == clip(x,-6,5.999988) (v_med3)
            int mi = (int)uu;                        // span 0..12; nonzero basis mi..mi+3
            float mf = (float)mi;
            float r = uu - mf;                       // in [0,1)
            float N0, N1, N2, N3;
            if (__all(mi >= 3 && mi <= 9)) {
                // interior span: uniform cubic B-spline closed form
                float omr = 1.0f - r;
                float r2 = r * r, r3 = r2 * r;
                float o2 = omr * omr;
                N0 = o2 * omr * (1.0f / 6.0f);
                N3 = r3 * (1.0f / 6.0f);
                N1 = fmaf(0.5f, r3, (2.0f / 3.0f) - r2);
                N2 = 1.0f - N0 - N1 - N3;
            } else {
                // general clamped-knot recursion in u-space (integer knot gaps)
                float t13 = 13.0f - mf;
                float af = fminf(mf, 1.0f);
                float bf = fminf(mf, 2.0f);
                float cf = fminf(t13, 2.0f);
                float df = fminf(t13, 3.0f);
                float r1 = 1.0f - r;
                float l2 = r + af, rr2 = cf - r;
                float l3 = r + bf, rr3 = df - r;
                // deg 2
                float iv = (af == 0.0f) ? 1.0f : 0.5f;          // 1/(1+a)
                float T = r1 * iv;
                float M0 = r1 * T;
                float sv = l2 * T;
                float iv2 = (cf == 1.0f) ? 1.0f : 0.5f;         // 1/c2
                float T2 = r * iv2;
                float M1 = fmaf(rr2, T2, sv);
                float M2 = r * T2;
                // deg 3
                float iv3 = 0.5f;
                iv3 = (bf == 0.0f) ? 1.0f : iv3;                // 1/(1+b)
                iv3 = (bf == 2.0f) ? (1.0f / 3.0f) : iv3;
                T = M0 * iv3;
                N0 = r1 * T;
                sv = l3 * T;
                float g14 = af + cf;                            // a+c2 in {2,3}
                float iv4 = (g14 == 2.0f) ? 0.5f : (1.0f / 3.0f);
                T = M1 * iv4;
                N1 = fmaf(rr2, T, sv);
                sv = l2 * T;
                float iv5 = 0.5f;
                iv5 = (df == 1.0f) ? 1.0f : iv5;                // 1/d3
                iv5 = (df == 3.0f) ? (1.0f / 3.0f) : iv5;
                T = M2 * iv5;
                N2 = fmaf(rr3, T, sv);
                N3 = r * T;
            }
            // payload: g at f16 slots mi..mi+3 (dword pairs)
            float g0 = x * N0, g1 = x * N1, g2 = x * N2, g3 = x * N3;
            int e = mi & 1;
            float aa = e ? 0.0f : g0, bb = e ? g0 : g1;
            float cc = e ? g1 : g2, dd = e ? g2 : g3;
            float ee = e ? g3 : 0.0f;
            u32 p0 = __builtin_bit_cast(u32, __builtin_amdgcn_cvt_pkrtz(aa, bb));
            u32 p1 = __builtin_bit_cast(u32, __builtin_amdgcn_cvt_pkrtz(cc, dd));
            u32 p2 = __builtin_bit_cast(u32, __builtin_amdgcn_cvt_pkrtz(ee, 0.0f));
            int w0 = mi >> 1;
            int dlt = w0 & 1;
            // 4-dword container at even dword (w0&6), payload offset dlt
            u32 C0 = dlt ? 0u : p0;
            u32 C1 = dlt ? p0 : p1;
            u32 C2 = dlt ? p1 : p2;
            u32 C3 = dlt ? p2 : 0u;
            // rotate-place; XOR 4*(qp) folds the keep/send half-swap in for free
            int j0 = (w0 & 6) ^ (qp << 2);
            bool b2 = (j0 & 2) != 0;
            u32 t0 = b2 ? 0u : C0;
            u32 t1 = b2 ? 0u : C1;
            u32 t2 = b2 ? C0 : C2;
            u32 t3 = b2 ? C1 : C3;
            u32 t4 = b2 ? C2 : 0u;
            u32 t5 = b2 ? C3 : 0u;     // t6 = t7 = 0
            bool b4 = (j0 & 4) != 0;
            u32 B0 = b4 ? t4 : t0;
            u32 B1 = b4 ? t5 : t1;
            u32 B2 = b4 ? 0u : t2;
            u32 B3 = b4 ? 0u : t3;
            u32 B4 = b4 ? t0 : t4;
            u32 B5 = b4 ? t1 : t5;
            u32 B6 = b4 ? t2 : 0u;
            u32 B7 = b4 ? t3 : 0u;
            // exchange send-half with partner lane (q ^ 1)
            u32 R0 = (u32)__shfl_xor((int)B4, 16);
            u32 R1 = (u32)__shfl_xor((int)B5, 16);
            u32 R2 = (u32)__shfl_xor((int)B6, 16);
            u32 R3 = (u32)__shfl_xor((int)B7, 16);
            u32x4 kp = {B0, B1, B2, B3};
            u32x4 rc = {R0, R1, R2, R3};
            f16x8 ka = __builtin_bit_cast(f16x8, kp);
            f16x8 ra = __builtin_bit_cast(f16x8, rc);
            acc1 = __builtin_amdgcn_mfma_f32_16x16x32_f16(ka, bA[u][0], acc1, 0, 0, 0);
            acc1 = __builtin_amdgcn_mfma_f32_16x16x32_f16(ra, bA[u][1], acc1, 0, 0, 0);
            if (h == 0) {
                acc0 = __builtin_amdgcn_mfma_f32_16x16x32_f16(ka, bB[u][0], acc0, 0, 0, 0);
                acc0 = __builtin_amdgcn_mfma_f32_16x16x32_f16(ra, bB[u][1], acc0, 0, 0, 0);
            }
        }

        // ---- combine: h0 publishes its cols16-31 partial; h1 adds and stores
        if (h == 0) {
#pragma unroll
            for (int rI = 0; rI < 4; ++rI)
                P[i][pair][(q * 4 + rI) * 17 + s] = acc1[rI];
        }
        __syncthreads();

#pragma unroll
        for (int rI = 0; rI < 4; ++rI) {
            int bo = (T0 + q * 4 + rI) * 32;
            if (h == 0) {
                out[bo + s] = xe[rI] + acc0[rI];
            } else {
                out[bo + 16 + s] = xe[rI] + acc1[rI] + P[i][pair][(q * 4 + rI) * 17 + s];
            }
        }

        if (i == 0) {
#pragma unroll
            for (int u = 0; u < 4; ++u) xv[u] = xvn[u];
        }
    }
}

extern "C" void kernel_launch(void* const* d_in, const int* in_sizes, int n_in,
                              void* d_out, int out_size, void* d_ws, size_t ws_size,
                              hipStream_t stream) {
    const float* xin = (const float*)d_in[0];
    const float* params = (const float*)d_in[1];
    float* out = (float*)d_out;
    unsigned short* w2t = (unsigned short*)d_ws;   // 32*512 f16 = 32 KB scratch

    prep_w2t<<<64, 256, 0, stream>>>(params, w2t);
    decor_main<<<2048, 256, 0, stream>>>(xin, w2t, out);
}